// Round 6
// baseline (18.208 us; speedup 1.0000x reference)
//
#include <hip/hip_runtime.h>

// MarginRankingLoss over all B*B pairs.
// loss[m,n] = max(0, BIAS - 0.5*(w_m+w_n)*|p_m-p_n|)  (exact per-pair rewrite:
// the gt tie-break only affects r when diff==0, where r*diff==0 anyway).
//
// R6: packed-fp32 inner loop. MI355X 157.3 TF fp32 = 2x via v_pk_*_f32; we
// compute on float2 ext-vectors so the backend forms v_pk_add/v_pk_fma.
// Hinge trick: t1 = BIAS - w*d, t2 = BIAS + w*d, t1 + t2 = 2*BIAS > 0 so at
// most one is negative -> max(0, min(t1,t2)) == v_med3_f32(t1, t2, 0) exactly.
// Structure = R1 champion: 1024 wgs x 256 thr, full matrix, two-kernel reduce
// (R2/R3 more-wgs and R4 atomic-fuse both regressed).

#define BIAS_F 0.1f

typedef float v2f __attribute__((ext_vector_type(2)));

constexpr int TPB = 256;       // threads per block
constexpr int NPT = 8;         // n-values per thread (4 x float2 in registers)
constexpr int NG  = NPT / 2;   // float2 groups
constexpr int TN  = TPB * NPT; // 2048 n per tile
constexpr int TM  = 32;        // m per tile

__global__ __launch_bounds__(TPB) void pair_loss_kernel(
    const float* __restrict__ pred,
    const float* __restrict__ weight,
    float* __restrict__ partial,
    int B)
{
    const int n_base = blockIdx.x * TN;
    const int m_base = blockIdx.y * TM;
    const int t = threadIdx.x;

    v2f pn2[NG], wn2[NG], mask2[NG];

    if (n_base + TN <= B) {
        // Fast path: thread t owns n = n_base + 8t .. 8t+7 -> 4 coalesced
        // float4 loads (2 for pred, 2 for weight).
        const float4* p4 = reinterpret_cast<const float4*>(pred   + n_base) + 2 * t;
        const float4* w4 = reinterpret_cast<const float4*>(weight + n_base) + 2 * t;
        float4 pa = p4[0], pb = p4[1];
        float4 wa = w4[0], wb = w4[1];
        pn2[0] = (v2f){pa.x, pa.y}; pn2[1] = (v2f){pa.z, pa.w};
        pn2[2] = (v2f){pb.x, pb.y}; pn2[3] = (v2f){pb.z, pb.w};
        wn2[0] = (v2f){wa.x, wa.y} * 0.5f; wn2[1] = (v2f){wa.z, wa.w} * 0.5f;
        wn2[2] = (v2f){wb.x, wb.y} * 0.5f; wn2[3] = (v2f){wb.z, wb.w} * 0.5f;
        #pragma unroll
        for (int j = 0; j < NG; ++j) mask2[j] = (v2f){1.0f, 1.0f};
    } else {
        // General tail path (unused at B=8192).
        #pragma unroll
        for (int j = 0; j < NG; ++j) {
            #pragma unroll
            for (int e = 0; e < 2; ++e) {
                int n = n_base + 8 * t + 2 * j + e;
                bool ok = (n < B);
                int nc = ok ? n : 0;
                pn2[j][e]   = pred[nc];
                wn2[j][e]   = weight[nc] * 0.5f;
                mask2[j][e] = ok ? 1.0f : 0.0f;
            }
        }
    }

    v2f acc2[NG];
    #pragma unroll
    for (int j = 0; j < NG; ++j) acc2[j] = (v2f){0.0f, 0.0f};

    const v2f BIAS2 = (v2f){BIAS_F, BIAS_F};
    const int m_end = (m_base + TM <= B) ? TM : (B - m_base);

    #pragma unroll 4
    for (int i = 0; i < m_end; ++i) {
        const int m = m_base + i;
        const float pm  = pred[m];          // uniform -> scalar load
        const float wmh = weight[m] * 0.5f; // uniform
        const v2f pm2 = (v2f){pm, pm};
        const v2f wm2 = (v2f){wmh, wmh};
        #pragma unroll
        for (int j = 0; j < NG; ++j) {
            v2f d  = pm2 - pn2[j];                              // v_pk_add (neg)
            v2f w  = wm2 + wn2[j];                              // v_pk_add
            v2f t1 = __builtin_elementwise_fma(-w, d, BIAS2);   // v_pk_fma
            v2f t2 = __builtin_elementwise_fma( w, d, BIAS2);   // v_pk_fma
            v2f h;
            h.x = __builtin_amdgcn_fmed3f(t1.x, t2.x, 0.0f);    // v_med3_f32
            h.y = __builtin_amdgcn_fmed3f(t1.y, t2.y, 0.0f);    // v_med3_f32
            acc2[j] += h;                                        // v_pk_add
        }
    }

    float s = 0.0f;
    #pragma unroll
    for (int j = 0; j < NG; ++j)
        s += mask2[j].x * acc2[j].x + mask2[j].y * acc2[j].y;

    // wave (64-lane) reduction
    #pragma unroll
    for (int off = 32; off > 0; off >>= 1)
        s += __shfl_down(s, off, 64);

    __shared__ float lds[TPB / 64];
    const int lane = t & 63, wid = t >> 6;
    if (lane == 0) lds[wid] = s;
    __syncthreads();
    if (t == 0) {
        float bs = 0.0f;
        #pragma unroll
        for (int w = 0; w < TPB / 64; ++w) bs += lds[w];
        partial[blockIdx.y * gridDim.x + blockIdx.x] = bs;
    }
}

// One wave, no LDS, no barrier.
__global__ __launch_bounds__(64) void reduce_kernel(
    const float* __restrict__ partial, int n, float* __restrict__ out, int B)
{
    double s = 0.0;
    for (int i = (int)threadIdx.x; i < n; i += 64) s += (double)partial[i];
    #pragma unroll
    for (int off = 32; off > 0; off >>= 1)
        s += __shfl_down(s, off, 64);
    if (threadIdx.x == 0)
        out[0] = (float)(s / ((double)B * (double)B));
}

extern "C" void kernel_launch(void* const* d_in, const int* in_sizes, int n_in,
                              void* d_out, int out_size, void* d_ws, size_t ws_size,
                              hipStream_t stream) {
    const float* pred   = (const float*)d_in[0];
    // d_in[1] = correct_output — mathematically irrelevant (see header comment)
    const float* weight = (const float*)d_in[2];
    float* out = (float*)d_out;
    const int B = in_sizes[0];

    const int tilesN = (B + TN - 1) / TN;  // 4   at B=8192
    const int tilesM = (B + TM - 1) / TM;  // 256 at B=8192
    float* partial = (float*)d_ws;         // tilesN*tilesM floats (4 KB)

    dim3 grid(tilesN, tilesM);
    pair_loss_kernel<<<grid, TPB, 0, stream>>>(pred, weight, partial, B);
    reduce_kernel<<<1, 64, 0, stream>>>(partial, tilesN * tilesM, out, B);
}

// Round 7
// 18.019 us; speedup vs baseline: 1.0105x; 1.0105x over previous
//
#include <hip/hip_runtime.h>

// MarginRankingLoss over all B*B pairs.
// loss[m,n] = max(0, BIAS - 0.5*(w_m+w_n)*|p_m-p_n|)  (exact per-pair rewrite:
// the gt tie-break only affects r when diff==0, where r*diff==0 anyway).
//
// R7: same total waves / per-wave work as the R1 champion (4096 waves,
// 256 pairs/thread), but 512 wgs x 512 threads instead of 1024 x 256 —
// R2 showed wg dispatch count costs ~1.4 ns/wg, so halving dispatches is the
// only addressable term left. Inner loop = R6 packed fp32 + med3 hinge:
// t1 = BIAS - w*d, t2 = BIAS + w*d, t1+t2 = 2*BIAS > 0 => at most one
// negative => max(0, min(t1,t2)) == v_med3_f32(t1,t2,0) exactly.

#define BIAS_F 0.1f

typedef float v2f __attribute__((ext_vector_type(2)));

constexpr int TPB = 512;       // threads per block (8 waves)
constexpr int NPT = 8;         // n-values per thread (4 x float2)
constexpr int NG  = NPT / 2;   // float2 groups
constexpr int TN  = TPB * NPT; // 4096 n per tile
constexpr int TM  = 32;        // m per tile

__global__ __launch_bounds__(TPB) void pair_loss_kernel(
    const float* __restrict__ pred,
    const float* __restrict__ weight,
    float* __restrict__ partial,
    int B)
{
    const int n_base = blockIdx.x * TN;
    const int m_base = blockIdx.y * TM;
    const int t = threadIdx.x;

    v2f pn2[NG], wn2[NG], mask2[NG];

    if (n_base + TN <= B) {
        // Fast path: thread t owns n = n_base + 8t .. 8t+7 -> 4 coalesced
        // float4 loads.
        const float4* p4 = reinterpret_cast<const float4*>(pred   + n_base) + 2 * t;
        const float4* w4 = reinterpret_cast<const float4*>(weight + n_base) + 2 * t;
        float4 pa = p4[0], pb = p4[1];
        float4 wa = w4[0], wb = w4[1];
        pn2[0] = (v2f){pa.x, pa.y}; pn2[1] = (v2f){pa.z, pa.w};
        pn2[2] = (v2f){pb.x, pb.y}; pn2[3] = (v2f){pb.z, pb.w};
        wn2[0] = (v2f){wa.x, wa.y} * 0.5f; wn2[1] = (v2f){wa.z, wa.w} * 0.5f;
        wn2[2] = (v2f){wb.x, wb.y} * 0.5f; wn2[3] = (v2f){wb.z, wb.w} * 0.5f;
        #pragma unroll
        for (int j = 0; j < NG; ++j) mask2[j] = (v2f){1.0f, 1.0f};
    } else {
        // General tail path (unused at B=8192).
        #pragma unroll
        for (int j = 0; j < NG; ++j) {
            #pragma unroll
            for (int e = 0; e < 2; ++e) {
                int n = n_base + 8 * t + 2 * j + e;
                bool ok = (n < B);
                int nc = ok ? n : 0;
                pn2[j][e]   = pred[nc];
                wn2[j][e]   = weight[nc] * 0.5f;
                mask2[j][e] = ok ? 1.0f : 0.0f;
            }
        }
    }

    v2f acc2[NG];
    #pragma unroll
    for (int j = 0; j < NG; ++j) acc2[j] = (v2f){0.0f, 0.0f};

    const v2f BIAS2 = (v2f){BIAS_F, BIAS_F};
    const int m_end = (m_base + TM <= B) ? TM : (B - m_base);

    #pragma unroll 4
    for (int i = 0; i < m_end; ++i) {
        const int m = m_base + i;
        const float pm  = pred[m];          // uniform -> scalar load
        const float wmh = weight[m] * 0.5f; // uniform
        const v2f pm2 = (v2f){pm, pm};
        const v2f wm2 = (v2f){wmh, wmh};
        #pragma unroll
        for (int j = 0; j < NG; ++j) {
            v2f d  = pm2 - pn2[j];                              // v_pk_add (neg)
            v2f w  = wm2 + wn2[j];                              // v_pk_add
            v2f t1 = __builtin_elementwise_fma(-w, d, BIAS2);   // v_pk_fma
            v2f t2 = __builtin_elementwise_fma( w, d, BIAS2);   // v_pk_fma
            v2f h;
            h.x = __builtin_amdgcn_fmed3f(t1.x, t2.x, 0.0f);    // v_med3_f32
            h.y = __builtin_amdgcn_fmed3f(t1.y, t2.y, 0.0f);    // v_med3_f32
            acc2[j] += h;                                        // v_pk_add
        }
    }

    float s = 0.0f;
    #pragma unroll
    for (int j = 0; j < NG; ++j)
        s += mask2[j].x * acc2[j].x + mask2[j].y * acc2[j].y;

    // wave (64-lane) reduction
    #pragma unroll
    for (int off = 32; off > 0; off >>= 1)
        s += __shfl_down(s, off, 64);

    __shared__ float lds[TPB / 64];
    const int lane = t & 63, wid = t >> 6;
    if (lane == 0) lds[wid] = s;
    __syncthreads();
    if (t == 0) {
        float bs = 0.0f;
        #pragma unroll
        for (int w = 0; w < TPB / 64; ++w) bs += lds[w];
        partial[blockIdx.y * gridDim.x + blockIdx.x] = bs;
    }
}

// One wave, no LDS, no barrier.
__global__ __launch_bounds__(64) void reduce_kernel(
    const float* __restrict__ partial, int n, float* __restrict__ out, int B)
{
    double s = 0.0;
    for (int i = (int)threadIdx.x; i < n; i += 64) s += (double)partial[i];
    #pragma unroll
    for (int off = 32; off > 0; off >>= 1)
        s += __shfl_down(s, off, 64);
    if (threadIdx.x == 0)
        out[0] = (float)(s / ((double)B * (double)B));
}

extern "C" void kernel_launch(void* const* d_in, const int* in_sizes, int n_in,
                              void* d_out, int out_size, void* d_ws, size_t ws_size,
                              hipStream_t stream) {
    const float* pred   = (const float*)d_in[0];
    // d_in[1] = correct_output — mathematically irrelevant (see header comment)
    const float* weight = (const float*)d_in[2];
    float* out = (float*)d_out;
    const int B = in_sizes[0];

    const int tilesN = (B + TN - 1) / TN;  // 2   at B=8192
    const int tilesM = (B + TM - 1) / TM;  // 256 at B=8192
    float* partial = (float*)d_ws;         // tilesN*tilesM floats (2 KB)

    dim3 grid(tilesN, tilesM);             // 512 wgs x 512 thr = 4096 waves
    pair_loss_kernel<<<grid, TPB, 0, stream>>>(pred, weight, partial, B);
    reduce_kernel<<<1, 64, 0, stream>>>(partial, tilesN * tilesM, out, B);
}